// Round 2
// baseline (684.888 us; speedup 1.0000x reference)
//
#include <hip/hip_runtime.h>

#define BN_EPS 1e-5f

typedef __bf16 bf16x8 __attribute__((ext_vector_type(8)));
typedef float f32x4 __attribute__((ext_vector_type(4)));
typedef unsigned int uint;
typedef unsigned short ushort;

__device__ __forceinline__ ushort f2bf(float f) {
  union { float f; uint u; } v; v.f = f;
  uint r = v.u + 0x7FFF + ((v.u >> 16) & 1);   // RNE
  return (ushort)(r >> 16);
}
__device__ __forceinline__ float bf2f_lo(uint u) {
  union { uint i; float f; } v; v.i = u << 16; return v.f;
}
__device__ __forceinline__ float bf2f_hi(uint u) {
  union { uint i; float f; } v; v.i = u & 0xffff0000u; return v.f;
}
__device__ __forceinline__ uint pack2(float a, float b) {
  return (uint)f2bf(a) | ((uint)f2bf(b) << 16);
}

// ---------------- CSR build ----------------

__global__ void hist_kernel(const int* __restrict__ dst, int* __restrict__ cnt, int E) {
  int e = blockIdx.x * 256 + threadIdx.x;
  if (e < E) atomicAdd(&cnt[dst[e]], 1);
}

// One kernel: (a) blocks < NB reserve contiguous CSR ranges via wave-scan +
// single-cursor atomic bump (row order across nodes is irrelevant — only the
// per-node [beg, beg+deg) range matters; each 64-node group gets a contiguous
// range); (b) blocks >= NB run weight prep.
__global__ void reserve_prep_kernel(const int* __restrict__ cnt, int* __restrict__ rowbeg,
                                    int* __restrict__ cursor,
                                    const float* __restrict__ W_in, const float* __restrict__ Wl,
                                    const float* __restrict__ Wr, ushort* __restrict__ Bfm,
                                    int NB, int N) {
  int tid = threadIdx.x;
  int b = blockIdx.x;
  if (b >= NB) {
    // ---- weight prep: split-K fragment-major bf16 ----
    int p = (b - NB) * 256 + tid;
    int mat = p >> 12;
    int rem = p & 4095;
    int half = rem >> 11;
    int rem2 = rem & 2047;
    int nt = rem2 >> 8, kt2 = (rem2 >> 6) & 3, lane = rem2 & 63;
    int n = nt * 16 + (lane & 15);
    int k0 = (half * 4 + kt2) * 32 + (lane >> 4) * 8;
    ushort tmp[8];
    #pragma unroll
    for (int j = 0; j < 8; ++j) {
      int k = k0 + j;
      float v;
      if (mat == 0) v = W_in[k * 128 + n];
      else {
        int l = mat - 1;
        v = (k < 128) ? Wl[l * 16384 + k * 128 + n] : Wr[l * 16384 + (k - 128) * 128 + n];
      }
      tmp[j] = f2bf(v);
    }
    *(uint4*)&Bfm[(size_t)p * 8] = *(const uint4*)tmp;
    return;
  }
  int i = b * 256 + tid;
  int v = (i < N) ? cnt[i] : 0;
  int lane = tid & 63;
  int x = v;
  #pragma unroll
  for (int off = 1; off < 64; off <<= 1) {
    int y = __shfl_up(x, off, 64);
    if (lane >= off) x += y;
  }
  int ret = 0;
  if (lane == 63) ret = atomicAdd(cursor, x);
  int base = __shfl(ret, 63);
  if (i < N) rowbeg[i] = base + x - v;
}

__global__ void fill_kernel(const int* __restrict__ src, const int* __restrict__ dst,
                            const int* __restrict__ rowbeg, int* __restrict__ cur,
                            int* __restrict__ col, int E) {
  int e = blockIdx.x * 256 + threadIdx.x;
  if (e < E) {
    int d = dst[e];
    int p = rowbeg[d] + atomicAdd(&cur[d], 1);
    col[p] = src[e];
  }
}

// ---------------- fused mean-agg + MFMA GEMM (layers) ----------------------
// Each block owns 64 nodes. Phase 1: 8 half-waves gather/mean 8 nodes each
// into a swizzled LDS bf16 tile (the A0 operand, k in [0,128)). Phase 2: the
// original barrier-free split-K GEMM, with kt 0-3 A-fragments from LDS and
// kt 4-7 from h (lin_r). XOR swizzle idx^((row&7)<<3) (ushorts) keeps the
// ds_read_b128 fragment reads out of the 32-way row-stride bank conflict.
// LDS: Atile (16K, phases 1-2) and Cb (17.4K, epilogue) share one union —
// a __syncthreads() after the k-loop fences the reuse. 17408 B + <=80 VGPR
// => 6 blocks/CU, matching the ~6.1 blocks/CU grid.

template<bool F32OUT>
__global__ __launch_bounds__(256, 6)
void gemm_fused(const int* __restrict__ rowbeg, const int* __restrict__ deg,
                const int* __restrict__ col, const ushort* __restrict__ h,
                const ushort* __restrict__ Bfm, const float* __restrict__ bias,
                const float* __restrict__ gamma, const float* __restrict__ beta,
                const float* __restrict__ mean, const float* __restrict__ var,
                void* __restrict__ out, int N) {
  __shared__ __align__(16) char smem[4 * 16 * 68 * 4];   // 17408 B union
  ushort* Atile = (ushort*)smem;                         // 16384 B, phases 1-2
  float* Cb_all = (float*)smem;                          // 17408 B, epilogue
  int tid = threadIdx.x;
  int m0 = blockIdx.x * 64;

  // ---- phase 1: gather + mean into LDS ----
  {
    int hw = tid >> 5, l32 = tid & 31;
    const ushort* hp = h + l32 * 4;
    int node0 = m0 + hw * 8;
    int beg = 0, d = 0;
    if (node0 < N) { beg = rowbeg[node0]; d = deg[node0]; }
    #pragma unroll 1
    for (int i = 0; i < 8; ++i) {
      int r = hw * 8 + i;
      int node = m0 + r;
      // prefetch next node's range so the scalar loads overlap this gather
      int nbeg = 0, nd = 0;
      if (i < 7 && node + 1 < N) { nbeg = rowbeg[node + 1]; nd = deg[node + 1]; }
      if (node < N) {
        float di = 1.0f / (float)(d > 0 ? d : 1);
        float a0 = 0.f, a1 = 0.f, a2 = 0.f, a3 = 0.f;
        int e = beg, end = beg + d;
        for (; e + 3 < end; e += 4) {
          uint2 v0 = *(const uint2*)(hp + (size_t)col[e] * 128);
          uint2 v1 = *(const uint2*)(hp + (size_t)col[e + 1] * 128);
          uint2 v2 = *(const uint2*)(hp + (size_t)col[e + 2] * 128);
          uint2 v3 = *(const uint2*)(hp + (size_t)col[e + 3] * 128);
          a0 += (bf2f_lo(v0.x) + bf2f_lo(v1.x)) + (bf2f_lo(v2.x) + bf2f_lo(v3.x));
          a1 += (bf2f_hi(v0.x) + bf2f_hi(v1.x)) + (bf2f_hi(v2.x) + bf2f_hi(v3.x));
          a2 += (bf2f_lo(v0.y) + bf2f_lo(v1.y)) + (bf2f_lo(v2.y) + bf2f_lo(v3.y));
          a3 += (bf2f_hi(v0.y) + bf2f_hi(v1.y)) + (bf2f_hi(v2.y) + bf2f_hi(v3.y));
        }
        for (; e < end; ++e) {
          uint2 v0 = *(const uint2*)(hp + (size_t)col[e] * 128);
          a0 += bf2f_lo(v0.x); a1 += bf2f_hi(v0.x);
          a2 += bf2f_lo(v0.y); a3 += bf2f_hi(v0.y);
        }
        uint2 o;
        o.x = pack2(a0 * di, a1 * di);
        o.y = pack2(a2 * di, a3 * di);
        int widx = (r * 128 + l32 * 4) ^ ((r & 7) << 3);
        *(uint2*)&Atile[widx] = o;
      }
      beg = nbeg; d = nd;
    }
  }
  __syncthreads();

  // ---- phase 2: GEMM ----
  int wave = tid >> 6, lane = tid & 63;
  int wm = wave >> 1, wn = wave & 1, quad = lane >> 4, l16 = lane & 15;

  int rowm[2];
  #pragma unroll
  for (int mt = 0; mt < 2; ++mt) {
    int r = m0 + wm * 32 + mt * 16 + l16;
    rowm[mt] = r < N ? r : N - 1;
  }

  uint4 a_buf[2][2], b_buf[2][4];
  #pragma unroll
  for (int mt = 0; mt < 2; ++mt) {
    int lr = wm * 32 + mt * 16 + l16;
    a_buf[0][mt] = *(const uint4*)&Atile[(lr * 128 + quad * 8) ^ ((lr & 7) << 3)];
  }
  {
    const ushort* bp = Bfm + (size_t)(wn * 4 * 256 + lane) * 8;
    #pragma unroll
    for (int nt = 0; nt < 4; ++nt)
      b_buf[0][nt] = *(const uint4*)(bp + nt * 2048);
  }

  f32x4 acc[2][4] = {};

  #pragma unroll
  for (int kt = 0; kt < 8; ++kt) {
    if (kt < 7) {
      int k1 = kt + 1;
      if (k1 < 4) {
        int c = k1 * 32 + quad * 8;
        #pragma unroll
        for (int mt = 0; mt < 2; ++mt) {
          int lr = wm * 32 + mt * 16 + l16;
          a_buf[k1 & 1][mt] = *(const uint4*)&Atile[(lr * 128 + c) ^ ((lr & 7) << 3)];
        }
      } else {
        int ko = (k1 & 3) * 32 + quad * 8;
        #pragma unroll
        for (int mt = 0; mt < 2; ++mt)
          a_buf[k1 & 1][mt] = *(const uint4*)(h + (size_t)rowm[mt] * 128 + ko);
      }
      const ushort* bp = Bfm + ((size_t)(k1 >> 2) * 16384 +
                                (size_t)((wn * 4) * 256 + (k1 & 3) * 64 + lane) * 8);
      #pragma unroll
      for (int nt = 0; nt < 4; ++nt)
        b_buf[k1 & 1][nt] = *(const uint4*)(bp + nt * 2048);
    }
    __builtin_amdgcn_sched_barrier(0);   // loads stay issued ahead of the MFMAs
    #pragma unroll
    for (int mt = 0; mt < 2; ++mt) {
      bf16x8 af = __builtin_bit_cast(bf16x8, a_buf[kt & 1][mt]);
      #pragma unroll
      for (int nt = 0; nt < 4; ++nt)
        acc[mt][nt] = __builtin_amdgcn_mfma_f32_16x16x32_bf16(
            af, __builtin_bit_cast(bf16x8, b_buf[kt & 1][nt]), acc[mt][nt], 0, 0, 0);
    }
  }

  // fence: all waves done reading Atile before Cb overwrites the union
  __syncthreads();

  // bias + BN + ReLU in registers
  #pragma unroll
  for (int nt = 0; nt < 4; ++nt) {
    int c = wn * 64 + nt * 16 + l16;
    float sc = gamma[c] * rsqrtf(var[c] + BN_EPS);
    float sh = beta[c] - mean[c] * sc;
    float bi = bias[c];
    #pragma unroll
    for (int mt = 0; mt < 2; ++mt)
      #pragma unroll
      for (int r = 0; r < 4; ++r)
        acc[mt][nt][r] = fmaxf((acc[mt][nt][r] + bi) * sc + sh, 0.f);
  }

  // per-wave LDS bounce for vectorized residual+store (no barriers)
  float* Cb = Cb_all + wave * (16 * 68);
  #pragma unroll
  for (int mt = 0; mt < 2; ++mt) {
    #pragma unroll
    for (int nt = 0; nt < 4; ++nt)
      #pragma unroll
      for (int r = 0; r < 4; ++r)
        Cb[(quad * 4 + r) * 68 + nt * 16 + l16] = acc[mt][nt][r];
    #pragma unroll
    for (int i = 0; i < 4; ++i) {
      int idx = i * 64 + lane, rowl = idx >> 4, seg = idx & 15;
      int grow = m0 + wm * 32 + mt * 16 + rowl;
      if (grow < N) {
        float4 vv = *(float4*)&Cb[rowl * 68 + seg * 4];
        uint2 rv = *(const uint2*)(h + (size_t)grow * 128 + wn * 64 + seg * 4);
        vv.x += bf2f_lo(rv.x); vv.y += bf2f_hi(rv.x);
        vv.z += bf2f_lo(rv.y); vv.w += bf2f_hi(rv.y);
        if (F32OUT) {
          *(float4*)((float*)out + (size_t)grow * 128 + wn * 64 + seg * 4) = vv;
        } else {
          uint2 o;
          o.x = pack2(vv.x, vv.y); o.y = pack2(vv.z, vv.w);
          *(uint2*)((ushort*)out + (size_t)grow * 128 + wn * 64 + seg * 4) = o;
        }
      }
    }
  }
}

// ---------------- MFMA GEMM (input proj): x fp32, BM=64, barrier-free ---------

__global__ __launch_bounds__(256, 4)
void gemm_in(const float* __restrict__ X, const ushort* __restrict__ Bfm,
             const float* __restrict__ bias,
             const float* __restrict__ gamma, const float* __restrict__ beta,
             const float* __restrict__ mean, const float* __restrict__ var,
             ushort* __restrict__ out, int N) {
  __shared__ float Cb_all[4 * 16 * 68];
  int tid = threadIdx.x, wave = tid >> 6, lane = tid & 63;
  int wm = wave >> 1, wn = wave & 1, quad = lane >> 4, l16 = lane & 15;
  int m0 = blockIdx.x * 64;

  int rowm[2];
  #pragma unroll
  for (int mt = 0; mt < 2; ++mt) {
    int r = m0 + wm * 32 + mt * 16 + l16;
    rowm[mt] = r < N ? r : N - 1;
  }

  float4 f_buf[2][2][2];
  uint4 b_buf[2][4];
  #pragma unroll
  for (int mt = 0; mt < 2; ++mt) {
    const float* p = X + (size_t)rowm[mt] * 256 + quad * 8;
    f_buf[0][mt][0] = *(const float4*)p;
    f_buf[0][mt][1] = *(const float4*)(p + 4);
  }
  {
    const ushort* bp = Bfm + (size_t)(wn * 4 * 256 + lane) * 8;
    #pragma unroll
    for (int nt = 0; nt < 4; ++nt)
      b_buf[0][nt] = *(const uint4*)(bp + nt * 2048);
  }

  f32x4 acc[2][4] = {};

  #pragma unroll
  for (int kt = 0; kt < 8; ++kt) {
    if (kt < 7) {
      int k1 = kt + 1;
      int ko = k1 * 32 + quad * 8;
      #pragma unroll
      for (int mt = 0; mt < 2; ++mt) {
        const float* p = X + (size_t)rowm[mt] * 256 + ko;
        f_buf[k1 & 1][mt][0] = *(const float4*)p;
        f_buf[k1 & 1][mt][1] = *(const float4*)(p + 4);
      }
      const ushort* bp = Bfm + ((size_t)(k1 >> 2) * 16384 +
                                (size_t)((wn * 4) * 256 + (k1 & 3) * 64 + lane) * 8);
      #pragma unroll
      for (int nt = 0; nt < 4; ++nt)
        b_buf[k1 & 1][nt] = *(const uint4*)(bp + nt * 2048);
    }
    __builtin_amdgcn_sched_barrier(0);
    #pragma unroll
    for (int mt = 0; mt < 2; ++mt) {
      float4 lo = f_buf[kt & 1][mt][0], hi = f_buf[kt & 1][mt][1];
      uint4 av;
      av.x = pack2(lo.x, lo.y); av.y = pack2(lo.z, lo.w);
      av.z = pack2(hi.x, hi.y); av.w = pack2(hi.z, hi.w);
      bf16x8 af = __builtin_bit_cast(bf16x8, av);
      #pragma unroll
      for (int nt = 0; nt < 4; ++nt)
        acc[mt][nt] = __builtin_amdgcn_mfma_f32_16x16x32_bf16(
            af, __builtin_bit_cast(bf16x8, b_buf[kt & 1][nt]), acc[mt][nt], 0, 0, 0);
    }
  }

  #pragma unroll
  for (int nt = 0; nt < 4; ++nt) {
    int c = wn * 64 + nt * 16 + l16;
    float sc = gamma[c] * rsqrtf(var[c] + BN_EPS);
    float sh = beta[c] - mean[c] * sc;
    float bi = bias[c];
    #pragma unroll
    for (int mt = 0; mt < 2; ++mt)
      #pragma unroll
      for (int r = 0; r < 4; ++r)
        acc[mt][nt][r] = fmaxf((acc[mt][nt][r] + bi) * sc + sh, 0.f);
  }

  float* Cb = Cb_all + wave * (16 * 68);
  #pragma unroll
  for (int mt = 0; mt < 2; ++mt) {
    #pragma unroll
    for (int nt = 0; nt < 4; ++nt)
      #pragma unroll
      for (int r = 0; r < 4; ++r)
        Cb[(quad * 4 + r) * 68 + nt * 16 + l16] = acc[mt][nt][r];
    #pragma unroll
    for (int i = 0; i < 4; ++i) {
      int idx = i * 64 + lane, rowl = idx >> 4, seg = idx & 15;
      int grow = m0 + wm * 32 + mt * 16 + rowl;
      if (grow < N) {
        float4 vv = *(float4*)&Cb[rowl * 68 + seg * 4];
        uint2 o;
        o.x = pack2(vv.x, vv.y); o.y = pack2(vv.z, vv.w);
        *(uint2*)(out + (size_t)grow * 128 + wn * 64 + seg * 4) = o;
      }
    }
  }
}

// ---------------- launch ----------------

extern "C" void kernel_launch(void* const* d_in, const int* in_sizes, int n_in,
                              void* d_out, int out_size, void* d_ws, size_t ws_size,
                              hipStream_t stream) {
  const float* x      = (const float*)d_in[0];
  const int*   eidx   = (const int*)d_in[1];
  const float* W_in   = (const float*)d_in[2];
  const float* b_in   = (const float*)d_in[3];
  const float* bng_in = (const float*)d_in[4];
  const float* bnb_in = (const float*)d_in[5];
  const float* bnm_in = (const float*)d_in[6];
  const float* bnv_in = (const float*)d_in[7];
  const float* Wl     = (const float*)d_in[8];
  const float* bl     = (const float*)d_in[9];
  const float* Wr     = (const float*)d_in[10];
  const float* bng    = (const float*)d_in[11];
  const float* bnb    = (const float*)d_in[12];
  const float* bnm    = (const float*)d_in[13];
  const float* bnv    = (const float*)d_in[14];

  const int N = in_sizes[0] / 256;
  const int E = in_sizes[1] / 2;
  const int NB = (N + 255) / 256;
  const int* src = eidx;
  const int* dst = eidx + E;

  char* ws = (char*)d_ws;
  size_t off = 0;
  auto alloc = [&](size_t bytes) {
    void* p = ws + off;
    off = (off + bytes + 255) & ~(size_t)255;
    return p;
  };
  int* zreg     = (int*)alloc((size_t)(2 * N + 1) * 4);   // cnt | cur | cursor
  int* cnt      = zreg;
  int* cur      = zreg + N;
  int* cursor   = zreg + 2 * N;
  int* rowbeg   = (int*)alloc((size_t)N * 4);
  int* col      = (int*)alloc((size_t)E * 4);
  ushort* Bfm   = (ushort*)alloc(4 * 32768 * 2);   // split-K frag-major: [in, l0, l1, l2]
  ushort* hA    = (ushort*)alloc((size_t)N * 128 * 2);
  ushort* hB    = (ushort*)alloc((size_t)N * 128 * 2);
  (void)ws_size; (void)n_in; (void)out_size;

  const int EB = (E + 255) / 256;
  const int GB = (N + 63) / 64;

  // CSR build (bump allocation — row order irrelevant) + weight prep folded in
  hipMemsetAsync(zreg, 0, (size_t)(2 * N + 1) * 4, stream);
  hist_kernel<<<EB, 256, 0, stream>>>(dst, cnt, E);
  reserve_prep_kernel<<<NB + 64, 256, 0, stream>>>(cnt, rowbeg, cursor,
                                                   W_in, Wl, Wr, Bfm, NB, N);
  fill_kernel<<<EB, 256, 0, stream>>>(src, dst, rowbeg, cur, col, E);

  // input projection
  gemm_in<<<GB, 256, 0, stream>>>(x, Bfm, b_in, bng_in, bnb_in, bnm_in, bnv_in, hA, N);

  // 3 SAGE layers, aggregation fused into the GEMM: hA -> hB -> hA -> d_out(fp32)
  ushort* hbuf[2] = { hA, hB };
  for (int l = 0; l < 3; ++l) {
    const ushort* h_in = hbuf[l & 1];
    const ushort* BfmL = Bfm + (size_t)(l + 1) * 32768;
    const float* biasL = bl + l * 128;
    if (l < 2) {
      gemm_fused<false><<<GB, 256, 0, stream>>>(rowbeg, cnt, col, h_in, BfmL, biasL,
          bng + l * 128, bnb + l * 128, bnm + l * 128, bnv + l * 128,
          (void*)hbuf[(l + 1) & 1], N);
    } else {
      gemm_fused<true><<<GB, 256, 0, stream>>>(rowbeg, cnt, col, h_in, BfmL, biasL,
          bng + l * 128, bnb + l * 128, bnm + l * 128, bnv + l * 128,
          d_out, N);
    }
  }
}

// Round 3
// 514.023 us; speedup vs baseline: 1.3324x; 1.3324x over previous
//
#include <hip/hip_runtime.h>

#define BN_EPS 1e-5f

typedef __bf16 bf16x8 __attribute__((ext_vector_type(8)));
typedef float f32x4 __attribute__((ext_vector_type(4)));
typedef unsigned int uint;
typedef unsigned short ushort;

__device__ __forceinline__ ushort f2bf(float f) {
  union { float f; uint u; } v; v.f = f;
  uint r = v.u + 0x7FFF + ((v.u >> 16) & 1);   // RNE
  return (ushort)(r >> 16);
}
__device__ __forceinline__ float bf2f_lo(uint u) {
  union { uint i; float f; } v; v.i = u << 16; return v.f;
}
__device__ __forceinline__ float bf2f_hi(uint u) {
  union { uint i; float f; } v; v.i = u & 0xffff0000u; return v.f;
}
__device__ __forceinline__ uint pack2(float a, float b) {
  return (uint)f2bf(a) | ((uint)f2bf(b) << 16);
}

// ---------------- CSR build ----------------

__global__ void hist_kernel(const int* __restrict__ dst, int* __restrict__ cnt, int E) {
  int e = blockIdx.x * 256 + threadIdx.x;
  if (e < E) atomicAdd(&cnt[dst[e]], 1);
}

// One kernel: (a) blocks < NB reserve contiguous CSR ranges via wave-scan +
// single-cursor atomic bump (row order across nodes is irrelevant — only the
// per-node [beg, beg+deg) range matters); (b) blocks >= NB run weight prep.
__global__ void reserve_prep_kernel(const int* __restrict__ cnt, int* __restrict__ rowbeg,
                                    int* __restrict__ cursor,
                                    const float* __restrict__ W_in, const float* __restrict__ Wl,
                                    const float* __restrict__ Wr, ushort* __restrict__ Bfm,
                                    int NB, int N) {
  int tid = threadIdx.x;
  int b = blockIdx.x;
  if (b >= NB) {
    // ---- weight prep: split-K fragment-major bf16 ----
    int p = (b - NB) * 256 + tid;
    int mat = p >> 12;
    int rem = p & 4095;
    int half = rem >> 11;
    int rem2 = rem & 2047;
    int nt = rem2 >> 8, kt2 = (rem2 >> 6) & 3, lane = rem2 & 63;
    int n = nt * 16 + (lane & 15);
    int k0 = (half * 4 + kt2) * 32 + (lane >> 4) * 8;
    ushort tmp[8];
    #pragma unroll
    for (int j = 0; j < 8; ++j) {
      int k = k0 + j;
      float v;
      if (mat == 0) v = W_in[k * 128 + n];
      else {
        int l = mat - 1;
        v = (k < 128) ? Wl[l * 16384 + k * 128 + n] : Wr[l * 16384 + (k - 128) * 128 + n];
      }
      tmp[j] = f2bf(v);
    }
    *(uint4*)&Bfm[(size_t)p * 8] = *(const uint4*)tmp;
    return;
  }
  int i = b * 256 + tid;
  int v = (i < N) ? cnt[i] : 0;
  int lane = tid & 63;
  int x = v;
  #pragma unroll
  for (int off = 1; off < 64; off <<= 1) {
    int y = __shfl_up(x, off, 64);
    if (lane >= off) x += y;
  }
  int ret = 0;
  if (lane == 63) ret = atomicAdd(cursor, x);
  int base = __shfl(ret, 63);
  if (i < N) rowbeg[i] = base + x - v;
}

__global__ void fill_kernel(const int* __restrict__ src, const int* __restrict__ dst,
                            const int* __restrict__ rowbeg, int* __restrict__ cur,
                            int* __restrict__ col, int E) {
  int e = blockIdx.x * 256 + threadIdx.x;
  if (e < E) {
    int d = dst[e];
    int p = rowbeg[d] + atomicAdd(&cur[d], 1);
    col[p] = src[e];
  }
}

// ---------------- fused mean-agg + MFMA GEMM (layers) ----------------------
// Each block owns 64 nodes. Phase 1: 8 half-waves gather/mean 8 nodes each
// into a swizzled LDS bf16 tile (the A0 operand, k in [0,128)). Phase 2: the
// original barrier-free split-K GEMM, with kt 0-3 A-fragments from LDS and
// kt 4-7 from h (lin_r). XOR swizzle idx^((row&7)<<3) (ushorts) keeps the
// ds_read_b128 fragment reads out of the 32-way row-stride bank conflict.
// LDS: Atile (16K, phases 1-2) and Cb (17.4K, epilogue) share one union —
// a __syncthreads() after the k-loop fences the reuse.
// __launch_bounds__(256,4): the min-waves hint stays LOW so the allocator
// keeps the kernel's natural ~60 VGPRs (<=64 => 8 waves/SIMD achievable by
// hardware; round-2's (256,6) forced 40 VGPRs -> scratch spills, WRITE_SIZE
// 50->250 MB). With 17408 B LDS (9 blocks/CU) + <=64 VGPR (8 blocks/CU),
// the whole 1563-block grid (~6.1/CU) is co-resident.

template<bool F32OUT>
__global__ __launch_bounds__(256, 4)
void gemm_fused(const int* __restrict__ rowbeg, const int* __restrict__ deg,
                const int* __restrict__ col, const ushort* __restrict__ h,
                const ushort* __restrict__ Bfm, const float* __restrict__ bias,
                const float* __restrict__ gamma, const float* __restrict__ beta,
                const float* __restrict__ mean, const float* __restrict__ var,
                void* __restrict__ out, int N) {
  __shared__ __align__(16) char smem[4 * 16 * 68 * 4];   // 17408 B union
  ushort* Atile = (ushort*)smem;                         // 16384 B, phases 1-2
  float* Cb_all = (float*)smem;                          // 17408 B, epilogue
  int tid = threadIdx.x;
  int m0 = blockIdx.x * 64;

  // ---- phase 1: gather + mean into LDS ----
  {
    int hw = tid >> 5, l32 = tid & 31;
    const ushort* hp = h + l32 * 4;
    int node0 = m0 + hw * 8;
    int beg = 0, d = 0;
    if (node0 < N) { beg = rowbeg[node0]; d = deg[node0]; }
    #pragma unroll 1
    for (int i = 0; i < 8; ++i) {
      int r = hw * 8 + i;
      int node = m0 + r;
      // prefetch next node's range so the scalar loads overlap this gather
      int nbeg = 0, nd = 0;
      if (i < 7 && node + 1 < N) { nbeg = rowbeg[node + 1]; nd = deg[node + 1]; }
      if (node < N) {
        float di = 1.0f / (float)(d > 0 ? d : 1);
        float a0 = 0.f, a1 = 0.f, a2 = 0.f, a3 = 0.f;
        int e = beg, end = beg + d;
        for (; e + 3 < end; e += 4) {
          uint2 v0 = *(const uint2*)(hp + (size_t)col[e] * 128);
          uint2 v1 = *(const uint2*)(hp + (size_t)col[e + 1] * 128);
          uint2 v2 = *(const uint2*)(hp + (size_t)col[e + 2] * 128);
          uint2 v3 = *(const uint2*)(hp + (size_t)col[e + 3] * 128);
          a0 += (bf2f_lo(v0.x) + bf2f_lo(v1.x)) + (bf2f_lo(v2.x) + bf2f_lo(v3.x));
          a1 += (bf2f_hi(v0.x) + bf2f_hi(v1.x)) + (bf2f_hi(v2.x) + bf2f_hi(v3.x));
          a2 += (bf2f_lo(v0.y) + bf2f_lo(v1.y)) + (bf2f_lo(v2.y) + bf2f_lo(v3.y));
          a3 += (bf2f_hi(v0.y) + bf2f_hi(v1.y)) + (bf2f_hi(v2.y) + bf2f_hi(v3.y));
        }
        for (; e < end; ++e) {
          uint2 v0 = *(const uint2*)(hp + (size_t)col[e] * 128);
          a0 += bf2f_lo(v0.x); a1 += bf2f_hi(v0.x);
          a2 += bf2f_lo(v0.y); a3 += bf2f_hi(v0.y);
        }
        uint2 o;
        o.x = pack2(a0 * di, a1 * di);
        o.y = pack2(a2 * di, a3 * di);
        int widx = (r * 128 + l32 * 4) ^ ((r & 7) << 3);
        *(uint2*)&Atile[widx] = o;
      }
      beg = nbeg; d = nd;
    }
  }
  __syncthreads();

  // ---- phase 2: GEMM ----
  int wave = tid >> 6, lane = tid & 63;
  int wm = wave >> 1, wn = wave & 1, quad = lane >> 4, l16 = lane & 15;

  int rowm[2];
  #pragma unroll
  for (int mt = 0; mt < 2; ++mt) {
    int r = m0 + wm * 32 + mt * 16 + l16;
    rowm[mt] = r < N ? r : N - 1;
  }

  uint4 a_buf[2][2], b_buf[2][4];
  #pragma unroll
  for (int mt = 0; mt < 2; ++mt) {
    int lr = wm * 32 + mt * 16 + l16;
    a_buf[0][mt] = *(const uint4*)&Atile[(lr * 128 + quad * 8) ^ ((lr & 7) << 3)];
  }
  {
    const ushort* bp = Bfm + (size_t)(wn * 4 * 256 + lane) * 8;
    #pragma unroll
    for (int nt = 0; nt < 4; ++nt)
      b_buf[0][nt] = *(const uint4*)(bp + nt * 2048);
  }

  f32x4 acc[2][4] = {};

  #pragma unroll
  for (int kt = 0; kt < 8; ++kt) {
    if (kt < 7) {
      int k1 = kt + 1;
      if (k1 < 4) {
        int c = k1 * 32 + quad * 8;
        #pragma unroll
        for (int mt = 0; mt < 2; ++mt) {
          int lr = wm * 32 + mt * 16 + l16;
          a_buf[k1 & 1][mt] = *(const uint4*)&Atile[(lr * 128 + c) ^ ((lr & 7) << 3)];
        }
      } else {
        int ko = (k1 & 3) * 32 + quad * 8;
        #pragma unroll
        for (int mt = 0; mt < 2; ++mt)
          a_buf[k1 & 1][mt] = *(const uint4*)(h + (size_t)rowm[mt] * 128 + ko);
      }
      const ushort* bp = Bfm + ((size_t)(k1 >> 2) * 16384 +
                                (size_t)((wn * 4) * 256 + (k1 & 3) * 64 + lane) * 8);
      #pragma unroll
      for (int nt = 0; nt < 4; ++nt)
        b_buf[k1 & 1][nt] = *(const uint4*)(bp + nt * 2048);
    }
    __builtin_amdgcn_sched_barrier(0);   // loads stay issued ahead of the MFMAs
    #pragma unroll
    for (int mt = 0; mt < 2; ++mt) {
      bf16x8 af = __builtin_bit_cast(bf16x8, a_buf[kt & 1][mt]);
      #pragma unroll
      for (int nt = 0; nt < 4; ++nt)
        acc[mt][nt] = __builtin_amdgcn_mfma_f32_16x16x32_bf16(
            af, __builtin_bit_cast(bf16x8, b_buf[kt & 1][nt]), acc[mt][nt], 0, 0, 0);
    }
  }

  // fence: all waves done reading Atile before Cb overwrites the union
  __syncthreads();

  // bias + BN + ReLU in registers
  #pragma unroll
  for (int nt = 0; nt < 4; ++nt) {
    int c = wn * 64 + nt * 16 + l16;
    float sc = gamma[c] * rsqrtf(var[c] + BN_EPS);
    float sh = beta[c] - mean[c] * sc;
    float bi = bias[c];
    #pragma unroll
    for (int mt = 0; mt < 2; ++mt)
      #pragma unroll
      for (int r = 0; r < 4; ++r)
        acc[mt][nt][r] = fmaxf((acc[mt][nt][r] + bi) * sc + sh, 0.f);
  }

  // per-wave LDS bounce for vectorized residual+store (no barriers)
  float* Cb = Cb_all + wave * (16 * 68);
  #pragma unroll
  for (int mt = 0; mt < 2; ++mt) {
    #pragma unroll
    for (int nt = 0; nt < 4; ++nt)
      #pragma unroll
      for (int r = 0; r < 4; ++r)
        Cb[(quad * 4 + r) * 68 + nt * 16 + l16] = acc[mt][nt][r];
    #pragma unroll
    for (int i = 0; i < 4; ++i) {
      int idx = i * 64 + lane, rowl = idx >> 4, seg = idx & 15;
      int grow = m0 + wm * 32 + mt * 16 + rowl;
      if (grow < N) {
        float4 vv = *(float4*)&Cb[rowl * 68 + seg * 4];
        uint2 rv = *(const uint2*)(h + (size_t)grow * 128 + wn * 64 + seg * 4);
        vv.x += bf2f_lo(rv.x); vv.y += bf2f_hi(rv.x);
        vv.z += bf2f_lo(rv.y); vv.w += bf2f_hi(rv.y);
        if (F32OUT) {
          *(float4*)((float*)out + (size_t)grow * 128 + wn * 64 + seg * 4) = vv;
        } else {
          uint2 o;
          o.x = pack2(vv.x, vv.y); o.y = pack2(vv.z, vv.w);
          *(uint2*)((ushort*)out + (size_t)grow * 128 + wn * 64 + seg * 4) = o;
        }
      }
    }
  }
}

// ---------------- MFMA GEMM (input proj): x fp32, BM=64, barrier-free ---------

__global__ __launch_bounds__(256, 4)
void gemm_in(const float* __restrict__ X, const ushort* __restrict__ Bfm,
             const float* __restrict__ bias,
             const float* __restrict__ gamma, const float* __restrict__ beta,
             const float* __restrict__ mean, const float* __restrict__ var,
             ushort* __restrict__ out, int N) {
  __shared__ float Cb_all[4 * 16 * 68];
  int tid = threadIdx.x, wave = tid >> 6, lane = tid & 63;
  int wm = wave >> 1, wn = wave & 1, quad = lane >> 4, l16 = lane & 15;
  int m0 = blockIdx.x * 64;

  int rowm[2];
  #pragma unroll
  for (int mt = 0; mt < 2; ++mt) {
    int r = m0 + wm * 32 + mt * 16 + l16;
    rowm[mt] = r < N ? r : N - 1;
  }

  float4 f_buf[2][2][2];
  uint4 b_buf[2][4];
  #pragma unroll
  for (int mt = 0; mt < 2; ++mt) {
    const float* p = X + (size_t)rowm[mt] * 256 + quad * 8;
    f_buf[0][mt][0] = *(const float4*)p;
    f_buf[0][mt][1] = *(const float4*)(p + 4);
  }
  {
    const ushort* bp = Bfm + (size_t)(wn * 4 * 256 + lane) * 8;
    #pragma unroll
    for (int nt = 0; nt < 4; ++nt)
      b_buf[0][nt] = *(const uint4*)(bp + nt * 2048);
  }

  f32x4 acc[2][4] = {};

  #pragma unroll
  for (int kt = 0; kt < 8; ++kt) {
    if (kt < 7) {
      int k1 = kt + 1;
      int ko = k1 * 32 + quad * 8;
      #pragma unroll
      for (int mt = 0; mt < 2; ++mt) {
        const float* p = X + (size_t)rowm[mt] * 256 + ko;
        f_buf[k1 & 1][mt][0] = *(const float4*)p;
        f_buf[k1 & 1][mt][1] = *(const float4*)(p + 4);
      }
      const ushort* bp = Bfm + ((size_t)(k1 >> 2) * 16384 +
                                (size_t)((wn * 4) * 256 + (k1 & 3) * 64 + lane) * 8);
      #pragma unroll
      for (int nt = 0; nt < 4; ++nt)
        b_buf[k1 & 1][nt] = *(const uint4*)(bp + nt * 2048);
    }
    __builtin_amdgcn_sched_barrier(0);
    #pragma unroll
    for (int mt = 0; mt < 2; ++mt) {
      float4 lo = f_buf[kt & 1][mt][0], hi = f_buf[kt & 1][mt][1];
      uint4 av;
      av.x = pack2(lo.x, lo.y); av.y = pack2(lo.z, lo.w);
      av.z = pack2(hi.x, hi.y); av.w = pack2(hi.z, hi.w);
      bf16x8 af = __builtin_bit_cast(bf16x8, av);
      #pragma unroll
      for (int nt = 0; nt < 4; ++nt)
        acc[mt][nt] = __builtin_amdgcn_mfma_f32_16x16x32_bf16(
            af, __builtin_bit_cast(bf16x8, b_buf[kt & 1][nt]), acc[mt][nt], 0, 0, 0);
    }
  }

  #pragma unroll
  for (int nt = 0; nt < 4; ++nt) {
    int c = wn * 64 + nt * 16 + l16;
    float sc = gamma[c] * rsqrtf(var[c] + BN_EPS);
    float sh = beta[c] - mean[c] * sc;
    float bi = bias[c];
    #pragma unroll
    for (int mt = 0; mt < 2; ++mt)
      #pragma unroll
      for (int r = 0; r < 4; ++r)
        acc[mt][nt][r] = fmaxf((acc[mt][nt][r] + bi) * sc + sh, 0.f);
  }

  float* Cb = Cb_all + wave * (16 * 68);
  #pragma unroll
  for (int mt = 0; mt < 2; ++mt) {
    #pragma unroll
    for (int nt = 0; nt < 4; ++nt)
      #pragma unroll
      for (int r = 0; r < 4; ++r)
        Cb[(quad * 4 + r) * 68 + nt * 16 + l16] = acc[mt][nt][r];
    #pragma unroll
    for (int i = 0; i < 4; ++i) {
      int idx = i * 64 + lane, rowl = idx >> 4, seg = idx & 15;
      int grow = m0 + wm * 32 + mt * 16 + rowl;
      if (grow < N) {
        float4 vv = *(float4*)&Cb[rowl * 68 + seg * 4];
        uint2 o;
        o.x = pack2(vv.x, vv.y); o.y = pack2(vv.z, vv.w);
        *(uint2*)(out + (size_t)grow * 128 + wn * 64 + seg * 4) = o;
      }
    }
  }
}

// ---------------- launch ----------------

extern "C" void kernel_launch(void* const* d_in, const int* in_sizes, int n_in,
                              void* d_out, int out_size, void* d_ws, size_t ws_size,
                              hipStream_t stream) {
  const float* x      = (const float*)d_in[0];
  const int*   eidx   = (const int*)d_in[1];
  const float* W_in   = (const float*)d_in[2];
  const float* b_in   = (const float*)d_in[3];
  const float* bng_in = (const float*)d_in[4];
  const float* bnb_in = (const float*)d_in[5];
  const float* bnm_in = (const float*)d_in[6];
  const float* bnv_in = (const float*)d_in[7];
  const float* Wl     = (const float*)d_in[8];
  const float* bl     = (const float*)d_in[9];
  const float* Wr     = (const float*)d_in[10];
  const float* bng    = (const float*)d_in[11];
  const float* bnb    = (const float*)d_in[12];
  const float* bnm    = (const float*)d_in[13];
  const float* bnv    = (const float*)d_in[14];

  const int N = in_sizes[0] / 256;
  const int E = in_sizes[1] / 2;
  const int NB = (N + 255) / 256;
  const int* src = eidx;
  const int* dst = eidx + E;

  char* ws = (char*)d_ws;
  size_t off = 0;
  auto alloc = [&](size_t bytes) {
    void* p = ws + off;
    off = (off + bytes + 255) & ~(size_t)255;
    return p;
  };
  int* zreg     = (int*)alloc((size_t)(2 * N + 1) * 4);   // cnt | cur | cursor
  int* cnt      = zreg;
  int* cur      = zreg + N;
  int* cursor   = zreg + 2 * N;
  int* rowbeg   = (int*)alloc((size_t)N * 4);
  int* col      = (int*)alloc((size_t)E * 4);
  ushort* Bfm   = (ushort*)alloc(4 * 32768 * 2);   // split-K frag-major: [in, l0, l1, l2]
  ushort* hA    = (ushort*)alloc((size_t)N * 128 * 2);
  ushort* hB    = (ushort*)alloc((size_t)N * 128 * 2);
  (void)ws_size; (void)n_in; (void)out_size;

  const int EB = (E + 255) / 256;
  const int GB = (N + 63) / 64;

  // CSR build (bump allocation — row order irrelevant) + weight prep folded in
  hipMemsetAsync(zreg, 0, (size_t)(2 * N + 1) * 4, stream);
  hist_kernel<<<EB, 256, 0, stream>>>(dst, cnt, E);
  reserve_prep_kernel<<<NB + 64, 256, 0, stream>>>(cnt, rowbeg, cursor,
                                                   W_in, Wl, Wr, Bfm, NB, N);
  fill_kernel<<<EB, 256, 0, stream>>>(src, dst, rowbeg, cur, col, E);

  // input projection
  gemm_in<<<GB, 256, 0, stream>>>(x, Bfm, b_in, bng_in, bnb_in, bnm_in, bnv_in, hA, N);

  // 3 SAGE layers, aggregation fused into the GEMM: hA -> hB -> hA -> d_out(fp32)
  ushort* hbuf[2] = { hA, hB };
  for (int l = 0; l < 3; ++l) {
    const ushort* h_in = hbuf[l & 1];
    const ushort* BfmL = Bfm + (size_t)(l + 1) * 32768;
    const float* biasL = bl + l * 128;
    if (l < 2) {
      gemm_fused<false><<<GB, 256, 0, stream>>>(rowbeg, cnt, col, h_in, BfmL, biasL,
          bng + l * 128, bnb + l * 128, bnm + l * 128, bnv + l * 128,
          (void*)hbuf[(l + 1) & 1], N);
    } else {
      gemm_fused<true><<<GB, 256, 0, stream>>>(rowbeg, cnt, col, h_in, BfmL, biasL,
          bng + l * 128, bnb + l * 128, bnm + l * 128, bnv + l * 128,
          d_out, N);
    }
  }
}

// Round 4
// 468.028 us; speedup vs baseline: 1.4633x; 1.0983x over previous
//
#include <hip/hip_runtime.h>

#define BN_EPS 1e-5f

typedef __bf16 bf16x8 __attribute__((ext_vector_type(8)));
typedef float f32x4 __attribute__((ext_vector_type(4)));
typedef unsigned int uint;
typedef unsigned short ushort;

__device__ __forceinline__ ushort f2bf(float f) {
  union { float f; uint u; } v; v.f = f;
  uint r = v.u + 0x7FFF + ((v.u >> 16) & 1);   // RNE
  return (ushort)(r >> 16);
}
__device__ __forceinline__ float bf2f_lo(uint u) {
  union { uint i; float f; } v; v.i = u << 16; return v.f;
}
__device__ __forceinline__ float bf2f_hi(uint u) {
  union { uint i; float f; } v; v.i = u & 0xffff0000u; return v.f;
}
__device__ __forceinline__ uint pack2(float a, float b) {
  return (uint)f2bf(a) | ((uint)f2bf(b) << 16);
}

// ---------------- CSR build (bump allocation) ----------------

__global__ void hist_kernel(const int* __restrict__ dst, int* __restrict__ cnt, int E) {
  int e = blockIdx.x * 256 + threadIdx.x;
  if (e < E) atomicAdd(&cnt[dst[e]], 1);
}

// One kernel: (a) blocks < NB reserve contiguous CSR ranges via wave-scan +
// single-cursor atomic bump (row order across nodes is irrelevant — only the
// per-node [beg, beg+deg) range matters); (b) blocks >= NB run weight prep
// (split-K fragment-major bf16).
__global__ void reserve_prep_kernel(const int* __restrict__ cnt, int* __restrict__ rowbeg,
                                    int* __restrict__ cursor,
                                    const float* __restrict__ W_in, const float* __restrict__ Wl,
                                    const float* __restrict__ Wr, ushort* __restrict__ Bfm,
                                    int NB, int N) {
  int tid = threadIdx.x;
  int b = blockIdx.x;
  if (b >= NB) {
    int p = (b - NB) * 256 + tid;
    int mat = p >> 12;
    int rem = p & 4095;
    int half = rem >> 11;
    int rem2 = rem & 2047;
    int nt = rem2 >> 8, kt2 = (rem2 >> 6) & 3, lane = rem2 & 63;
    int n = nt * 16 + (lane & 15);
    int k0 = (half * 4 + kt2) * 32 + (lane >> 4) * 8;
    ushort tmp[8];
    #pragma unroll
    for (int j = 0; j < 8; ++j) {
      int k = k0 + j;
      float v;
      if (mat == 0) v = W_in[k * 128 + n];
      else {
        int l = mat - 1;
        v = (k < 128) ? Wl[l * 16384 + k * 128 + n] : Wr[l * 16384 + (k - 128) * 128 + n];
      }
      tmp[j] = f2bf(v);
    }
    *(uint4*)&Bfm[(size_t)p * 8] = *(const uint4*)tmp;
    return;
  }
  int i = b * 256 + tid;
  int v = (i < N) ? cnt[i] : 0;
  int lane = tid & 63;
  int x = v;
  #pragma unroll
  for (int off = 1; off < 64; off <<= 1) {
    int y = __shfl_up(x, off, 64);
    if (lane >= off) x += y;
  }
  int ret = 0;
  if (lane == 63) ret = atomicAdd(cursor, x);
  int base = __shfl(ret, 63);
  if (i < N) rowbeg[i] = base + x - v;
}

__global__ void fill_kernel(const int* __restrict__ src, const int* __restrict__ dst,
                            const int* __restrict__ rowbeg, int* __restrict__ cur,
                            int* __restrict__ col, int E) {
  int e = blockIdx.x * 256 + threadIdx.x;
  if (e < E) {
    int d = dst[e];
    int p = rowbeg[d] + atomicAdd(&cur[d], 1);
    col[p] = src[e];
  }
}

// ---------------- mean aggregation: 2 nodes per wave, deg inline ----------
// Oversubscribed grid (12500 blocks, ~49/CU with refill) keeps the gather at
// full 32-wave occupancy — this is what the fused variants (R1-R3) lost.

__global__ void agg_kernel(const int* __restrict__ rowbeg, const int* __restrict__ deg,
                           const int* __restrict__ col,
                           const ushort* __restrict__ h, ushort* __restrict__ agg, int N) {
  int node = blockIdx.x * 8 + (threadIdx.x >> 5);
  if (node >= N) return;
  int lane = threadIdx.x & 31;
  const ushort* hp = h + lane * 4;
  int beg = rowbeg[node];
  int d = deg[node];
  float di = 1.0f / (float)(d > 0 ? d : 1);
  float a0 = 0.f, a1 = 0.f, a2 = 0.f, a3 = 0.f;
  int e = beg, end = beg + d;
  for (; e + 3 < end; e += 4) {
    uint2 v0 = *(const uint2*)(hp + (size_t)col[e] * 128);
    uint2 v1 = *(const uint2*)(hp + (size_t)col[e + 1] * 128);
    uint2 v2 = *(const uint2*)(hp + (size_t)col[e + 2] * 128);
    uint2 v3 = *(const uint2*)(hp + (size_t)col[e + 3] * 128);
    a0 += (bf2f_lo(v0.x) + bf2f_lo(v1.x)) + (bf2f_lo(v2.x) + bf2f_lo(v3.x));
    a1 += (bf2f_hi(v0.x) + bf2f_hi(v1.x)) + (bf2f_hi(v2.x) + bf2f_hi(v3.x));
    a2 += (bf2f_lo(v0.y) + bf2f_lo(v1.y)) + (bf2f_lo(v2.y) + bf2f_lo(v3.y));
    a3 += (bf2f_hi(v0.y) + bf2f_hi(v1.y)) + (bf2f_hi(v2.y) + bf2f_hi(v3.y));
  }
  for (; e < end; ++e) {
    uint2 v0 = *(const uint2*)(hp + (size_t)col[e] * 128);
    a0 += bf2f_lo(v0.x); a1 += bf2f_hi(v0.x);
    a2 += bf2f_lo(v0.y); a3 += bf2f_hi(v0.y);
  }
  uint2 o;
  o.x = pack2(a0 * di, a1 * di);
  o.y = pack2(a2 * di, a3 * di);
  *(uint2*)(agg + (size_t)node * 128 + lane * 4) = o;
}

// ---------------- MFMA GEMM (layers): BM=64, barrier-free ---------------------
// 1563 blocks (~6/CU), 4 waves (2m x 2n), 32x64 per wave. B-frags from L2-hot
// frag-major global; A+B depth-1 double-buffer; per-wave epilogue LDS bounce.

template<bool F32OUT>
__global__ __launch_bounds__(256, 4)
void gemm_layer(const ushort* __restrict__ A0, const ushort* __restrict__ A1,
                const ushort* __restrict__ Bfm, const float* __restrict__ bias,
                const float* __restrict__ gamma, const float* __restrict__ beta,
                const float* __restrict__ mean, const float* __restrict__ var,
                const ushort* __restrict__ residual, void* __restrict__ out, int N) {
  __shared__ float Cb_all[4 * 16 * 68];
  int tid = threadIdx.x, wave = tid >> 6, lane = tid & 63;
  int wm = wave >> 1, wn = wave & 1, quad = lane >> 4, l16 = lane & 15;
  int m0 = blockIdx.x * 64;

  int rowm[2];
  #pragma unroll
  for (int mt = 0; mt < 2; ++mt) {
    int r = m0 + wm * 32 + mt * 16 + l16;
    rowm[mt] = r < N ? r : N - 1;
  }

  uint4 a_buf[2][2], b_buf[2][4];
  #pragma unroll
  for (int mt = 0; mt < 2; ++mt)
    a_buf[0][mt] = *(const uint4*)(A0 + (size_t)rowm[mt] * 128 + quad * 8);
  {
    const ushort* bp = Bfm + (size_t)(wn * 4 * 256 + lane) * 8;
    #pragma unroll
    for (int nt = 0; nt < 4; ++nt)
      b_buf[0][nt] = *(const uint4*)(bp + nt * 2048);
  }

  f32x4 acc[2][4] = {};

  #pragma unroll
  for (int kt = 0; kt < 8; ++kt) {
    if (kt < 7) {
      int k1 = kt + 1;
      const ushort* bse = (k1 < 4) ? A0 : A1;
      int ko = (k1 & 3) * 32 + quad * 8;
      #pragma unroll
      for (int mt = 0; mt < 2; ++mt)
        a_buf[k1 & 1][mt] = *(const uint4*)(bse + (size_t)rowm[mt] * 128 + ko);
      const ushort* bp = Bfm + ((size_t)(k1 >> 2) * 16384 +
                                (size_t)((wn * 4) * 256 + (k1 & 3) * 64 + lane) * 8);
      #pragma unroll
      for (int nt = 0; nt < 4; ++nt)
        b_buf[k1 & 1][nt] = *(const uint4*)(bp + nt * 2048);
    }
    __builtin_amdgcn_sched_barrier(0);   // loads stay issued ahead of the MFMAs
    #pragma unroll
    for (int mt = 0; mt < 2; ++mt) {
      bf16x8 af = __builtin_bit_cast(bf16x8, a_buf[kt & 1][mt]);
      #pragma unroll
      for (int nt = 0; nt < 4; ++nt)
        acc[mt][nt] = __builtin_amdgcn_mfma_f32_16x16x32_bf16(
            af, __builtin_bit_cast(bf16x8, b_buf[kt & 1][nt]), acc[mt][nt], 0, 0, 0);
    }
  }

  // bias + BN + ReLU in registers
  #pragma unroll
  for (int nt = 0; nt < 4; ++nt) {
    int c = wn * 64 + nt * 16 + l16;
    float sc = gamma[c] * rsqrtf(var[c] + BN_EPS);
    float sh = beta[c] - mean[c] * sc;
    float bi = bias[c];
    #pragma unroll
    for (int mt = 0; mt < 2; ++mt)
      #pragma unroll
      for (int r = 0; r < 4; ++r)
        acc[mt][nt][r] = fmaxf((acc[mt][nt][r] + bi) * sc + sh, 0.f);
  }

  // per-wave LDS bounce for vectorized residual+store (no barriers)
  float* Cb = Cb_all + wave * (16 * 68);
  #pragma unroll
  for (int mt = 0; mt < 2; ++mt) {
    #pragma unroll
    for (int nt = 0; nt < 4; ++nt)
      #pragma unroll
      for (int r = 0; r < 4; ++r)
        Cb[(quad * 4 + r) * 68 + nt * 16 + l16] = acc[mt][nt][r];
    #pragma unroll
    for (int i = 0; i < 4; ++i) {
      int idx = i * 64 + lane, rowl = idx >> 4, seg = idx & 15;
      int grow = m0 + wm * 32 + mt * 16 + rowl;
      if (grow < N) {
        float4 vv = *(float4*)&Cb[rowl * 68 + seg * 4];
        uint2 rv = *(const uint2*)(residual + (size_t)grow * 128 + wn * 64 + seg * 4);
        vv.x += bf2f_lo(rv.x); vv.y += bf2f_hi(rv.x);
        vv.z += bf2f_lo(rv.y); vv.w += bf2f_hi(rv.y);
        if (F32OUT) {
          *(float4*)((float*)out + (size_t)grow * 128 + wn * 64 + seg * 4) = vv;
        } else {
          uint2 o;
          o.x = pack2(vv.x, vv.y); o.y = pack2(vv.z, vv.w);
          *(uint2*)((ushort*)out + (size_t)grow * 128 + wn * 64 + seg * 4) = o;
        }
      }
    }
  }
}

// ---------------- MFMA GEMM (input proj): x fp32, BM=64, barrier-free ---------

__global__ __launch_bounds__(256, 4)
void gemm_in(const float* __restrict__ X, const ushort* __restrict__ Bfm,
             const float* __restrict__ bias,
             const float* __restrict__ gamma, const float* __restrict__ beta,
             const float* __restrict__ mean, const float* __restrict__ var,
             ushort* __restrict__ out, int N) {
  __shared__ float Cb_all[4 * 16 * 68];
  int tid = threadIdx.x, wave = tid >> 6, lane = tid & 63;
  int wm = wave >> 1, wn = wave & 1, quad = lane >> 4, l16 = lane & 15;
  int m0 = blockIdx.x * 64;

  int rowm[2];
  #pragma unroll
  for (int mt = 0; mt < 2; ++mt) {
    int r = m0 + wm * 32 + mt * 16 + l16;
    rowm[mt] = r < N ? r : N - 1;
  }

  float4 f_buf[2][2][2];
  uint4 b_buf[2][4];
  #pragma unroll
  for (int mt = 0; mt < 2; ++mt) {
    const float* p = X + (size_t)rowm[mt] * 256 + quad * 8;
    f_buf[0][mt][0] = *(const float4*)p;
    f_buf[0][mt][1] = *(const float4*)(p + 4);
  }
  {
    const ushort* bp = Bfm + (size_t)(wn * 4 * 256 + lane) * 8;
    #pragma unroll
    for (int nt = 0; nt < 4; ++nt)
      b_buf[0][nt] = *(const uint4*)(bp + nt * 2048);
  }

  f32x4 acc[2][4] = {};

  #pragma unroll
  for (int kt = 0; kt < 8; ++kt) {
    if (kt < 7) {
      int k1 = kt + 1;
      int ko = k1 * 32 + quad * 8;
      #pragma unroll
      for (int mt = 0; mt < 2; ++mt) {
        const float* p = X + (size_t)rowm[mt] * 256 + ko;
        f_buf[k1 & 1][mt][0] = *(const float4*)p;
        f_buf[k1 & 1][mt][1] = *(const float4*)(p + 4);
      }
      const ushort* bp = Bfm + ((size_t)(k1 >> 2) * 16384 +
                                (size_t)((wn * 4) * 256 + (k1 & 3) * 64 + lane) * 8);
      #pragma unroll
      for (int nt = 0; nt < 4; ++nt)
        b_buf[k1 & 1][nt] = *(const uint4*)(bp + nt * 2048);
    }
    __builtin_amdgcn_sched_barrier(0);
    #pragma unroll
    for (int mt = 0; mt < 2; ++mt) {
      float4 lo = f_buf[kt & 1][mt][0], hi = f_buf[kt & 1][mt][1];
      uint4 av;
      av.x = pack2(lo.x, lo.y); av.y = pack2(lo.z, lo.w);
      av.z = pack2(hi.x, hi.y); av.w = pack2(hi.z, hi.w);
      bf16x8 af = __builtin_bit_cast(bf16x8, av);
      #pragma unroll
      for (int nt = 0; nt < 4; ++nt)
        acc[mt][nt] = __builtin_amdgcn_mfma_f32_16x16x32_bf16(
            af, __builtin_bit_cast(bf16x8, b_buf[kt & 1][nt]), acc[mt][nt], 0, 0, 0);
    }
  }

  #pragma unroll
  for (int nt = 0; nt < 4; ++nt) {
    int c = wn * 64 + nt * 16 + l16;
    float sc = gamma[c] * rsqrtf(var[c] + BN_EPS);
    float sh = beta[c] - mean[c] * sc;
    float bi = bias[c];
    #pragma unroll
    for (int mt = 0; mt < 2; ++mt)
      #pragma unroll
      for (int r = 0; r < 4; ++r)
        acc[mt][nt][r] = fmaxf((acc[mt][nt][r] + bi) * sc + sh, 0.f);
  }

  float* Cb = Cb_all + wave * (16 * 68);
  #pragma unroll
  for (int mt = 0; mt < 2; ++mt) {
    #pragma unroll
    for (int nt = 0; nt < 4; ++nt)
      #pragma unroll
      for (int r = 0; r < 4; ++r)
        Cb[(quad * 4 + r) * 68 + nt * 16 + l16] = acc[mt][nt][r];
    #pragma unroll
    for (int i = 0; i < 4; ++i) {
      int idx = i * 64 + lane, rowl = idx >> 4, seg = idx & 15;
      int grow = m0 + wm * 32 + mt * 16 + rowl;
      if (grow < N) {
        float4 vv = *(float4*)&Cb[rowl * 68 + seg * 4];
        uint2 o;
        o.x = pack2(vv.x, vv.y); o.y = pack2(vv.z, vv.w);
        *(uint2*)(out + (size_t)grow * 128 + wn * 64 + seg * 4) = o;
      }
    }
  }
}

// ---------------- launch ----------------

extern "C" void kernel_launch(void* const* d_in, const int* in_sizes, int n_in,
                              void* d_out, int out_size, void* d_ws, size_t ws_size,
                              hipStream_t stream) {
  const float* x      = (const float*)d_in[0];
  const int*   eidx   = (const int*)d_in[1];
  const float* W_in   = (const float*)d_in[2];
  const float* b_in   = (const float*)d_in[3];
  const float* bng_in = (const float*)d_in[4];
  const float* bnb_in = (const float*)d_in[5];
  const float* bnm_in = (const float*)d_in[6];
  const float* bnv_in = (const float*)d_in[7];
  const float* Wl     = (const float*)d_in[8];
  const float* bl     = (const float*)d_in[9];
  const float* Wr     = (const float*)d_in[10];
  const float* bng    = (const float*)d_in[11];
  const float* bnb    = (const float*)d_in[12];
  const float* bnm    = (const float*)d_in[13];
  const float* bnv    = (const float*)d_in[14];

  const int N = in_sizes[0] / 256;
  const int E = in_sizes[1] / 2;
  const int NB = (N + 255) / 256;
  const int* src = eidx;
  const int* dst = eidx + E;

  char* ws = (char*)d_ws;
  size_t off = 0;
  auto alloc = [&](size_t bytes) {
    void* p = ws + off;
    off = (off + bytes + 255) & ~(size_t)255;
    return p;
  };
  int* zreg     = (int*)alloc((size_t)(2 * N + 1) * 4);   // cnt(deg) | cur | cursor
  int* cnt      = zreg;
  int* cur      = zreg + N;
  int* cursor   = zreg + 2 * N;
  int* rowbeg   = (int*)alloc((size_t)N * 4);
  int* col      = (int*)alloc((size_t)E * 4);
  ushort* Bfm   = (ushort*)alloc(4 * 32768 * 2);   // split-K frag-major: [in, l0, l1, l2]
  ushort* hA    = (ushort*)alloc((size_t)N * 128 * 2);
  ushort* hB    = (ushort*)alloc((size_t)N * 128 * 2);
  ushort* agg   = (ushort*)alloc((size_t)N * 128 * 2);
  (void)ws_size; (void)n_in; (void)out_size;

  const int EB = (E + 255) / 256;
  const int GB = (N + 63) / 64;

  // CSR build (bump allocation) + weight prep folded in
  hipMemsetAsync(zreg, 0, (size_t)(2 * N + 1) * 4, stream);
  hist_kernel<<<EB, 256, 0, stream>>>(dst, cnt, E);
  reserve_prep_kernel<<<NB + 64, 256, 0, stream>>>(cnt, rowbeg, cursor,
                                                   W_in, Wl, Wr, Bfm, NB, N);
  fill_kernel<<<EB, 256, 0, stream>>>(src, dst, rowbeg, cur, col, E);

  // input projection
  gemm_in<<<GB, 256, 0, stream>>>(x, Bfm, b_in, bng_in, bnb_in, bnm_in, bnv_in, hA, N);

  // 3 SAGE layers: hA -> hB -> hA -> d_out(fp32)
  ushort* hbuf[2] = { hA, hB };
  for (int l = 0; l < 3; ++l) {
    const ushort* h_in = hbuf[l & 1];
    agg_kernel<<<(N + 7) / 8, 256, 0, stream>>>(rowbeg, cnt, col, h_in, agg, N);
    const ushort* BfmL = Bfm + (size_t)(l + 1) * 32768;
    const float* biasL = bl + l * 128;
    if (l < 2) {
      gemm_layer<false><<<GB, 256, 0, stream>>>(agg, h_in, BfmL, biasL,
          bng + l * 128, bnb + l * 128, bnm + l * 128, bnv + l * 128,
          h_in, (void*)hbuf[(l + 1) & 1], N);
    } else {
      gemm_layer<true><<<GB, 256, 0, stream>>>(agg, h_in, BfmL, biasL,
          bng + l * 128, bnb + l * 128, bnm + l * 128, bnv + l * 128,
          h_in, d_out, N);
    }
  }
}